// Round 5
// baseline (908.544 us; speedup 1.0000x reference)
//
#include <hip/hip_runtime.h>

#define TOKENS 4096
#define IN_F   8192
#define OUT_F  8192

typedef int v4i  __attribute__((ext_vector_type(4)));
typedef int v16i __attribute__((ext_vector_type(16)));

__device__ __forceinline__ void gload_lds16(const void* g, void* l) {
    __builtin_amdgcn_global_load_lds(
        (const __attribute__((address_space(1))) void*)g,
        (__attribute__((address_space(3))) void*)l, 16, 0, 0);
}

// ---------------- Kernel 1: per-row absmax + int8 quantize ----------------
__global__ __launch_bounds__(256) void quant_kernel(const float* __restrict__ x,
                                                    signed char* __restrict__ xq,
                                                    float* __restrict__ recip_s) {
    const int row = blockIdx.x;
    const int t   = threadIdx.x;
    const float4* xr = (const float4*)(x + (size_t)row * IN_F);
    float4 v[8];
    float m = 0.f;
#pragma unroll
    for (int i = 0; i < 8; ++i) {
        v[i] = xr[t + 256 * i];
        m = fmaxf(m, fmaxf(fmaxf(fabsf(v[i].x), fabsf(v[i].y)),
                           fmaxf(fabsf(v[i].z), fabsf(v[i].w))));
    }
#pragma unroll
    for (int off = 32; off > 0; off >>= 1)
        m = fmaxf(m, __shfl_xor(m, off));
    __shared__ float wmax[4];
    if ((t & 63) == 0) wmax[t >> 6] = m;
    __syncthreads();
    m = fmaxf(fmaxf(wmax[0], wmax[1]), fmaxf(wmax[2], wmax[3]));
    m = fmaxf(m, 1e-5f);
    const float s = 127.0f / m;          // matches ref: s = 127/clip(max,1e-5)
    if (t == 0) recip_s[row] = m / 127.0f;
    unsigned int* out = (unsigned int*)(xq + (size_t)row * IN_F);
#pragma unroll
    for (int i = 0; i < 8; ++i) {
        int a = (int)fminf(fmaxf(rintf(v[i].x * s), -128.f), 127.f);
        int b = (int)fminf(fmaxf(rintf(v[i].y * s), -128.f), 127.f);
        int c = (int)fminf(fmaxf(rintf(v[i].z * s), -128.f), 127.f);
        int d = (int)fminf(fmaxf(rintf(v[i].w * s), -128.f), 127.f);
        out[t + 256 * i] = (a & 255) | ((b & 255) << 8) | ((c & 255) << 16) | ((d & 255) << 24);
    }
}

// ---------------- Kernel 2: weight int32 {0,1} -> int8 ----------------
__global__ __launch_bounds__(256) void pack_w(const int* __restrict__ w,
                                              unsigned int* __restrict__ w8) {
    const size_t idx = (size_t)blockIdx.x * 256 + threadIdx.x;
    int4 a = ((const int4*)w)[idx];
    w8[idx] = (a.x & 255) | ((a.y & 255) << 8) | ((a.z & 255) << 16) | ((a.w & 255) << 24);
}

// ---------------- Kernel 3: i8 GEMM, 256x256 block, 128x128/wave ----------
// 4 waves, each 4x4 of mfma_i32_32x32x32_i8 (acc = 256 VGPRs, 1 wave/SIMD).
// BK=64 (2 k-steps of 32). Double-buffered LDS (64 KB), raw s_barrier +
// hand waitcnt pipeline: prefetch tile k+1 (8 loads) stays in flight across
// the barrier; vmcnt(8) waits only the 8 loads of tile k issued last iter.
// LDS chunk swizzle: 16B chunk g of row r stored at position g ^ ((r>>1)&3).
__global__ __launch_bounds__(256, 1) void gemm_kernel(const signed char* __restrict__ A,
                                                      const signed char* __restrict__ B,
                                                      const float* __restrict__ recip_s,
                                                      const float* __restrict__ wscale,
                                                      const float* __restrict__ bias,
                                                      float* __restrict__ out) {
    __shared__ signed char As[2 * 256 * 64];   // 32 KB
    __shared__ signed char Bs[2 * 256 * 64];   // 32 KB
    const int t    = threadIdx.x;
    const int wave = t >> 6;
    const int lane = t & 63;
    const int m0 = blockIdx.y * 256;
    const int n0 = blockIdx.x * 256;
    const int wm = (wave >> 1) * 128;   // wave row offset (M)
    const int wn = (wave & 1) * 128;    // wave col offset (N)

    v16i acc[4][4] = {};                // 256 acc VGPRs

    // staging: each call 256 threads x 16B = 4KB (64 rows x 64B); 4 calls per matrix
    const int rowS = t >> 2;                           // 0..63
    const int colS = ((t & 3) ^ ((t >> 3) & 3)) * 16;  // swizzled source chunk
    const signed char* gA = A + (size_t)(m0 + rowS) * IN_F + colS;
    const signed char* gB = B + (size_t)(n0 + rowS) * IN_F + colS;
    signed char* lA = As + t * 16;                     // linear dest (HW constraint)
    signed char* lB = Bs + t * 16;

    const int rl = lane & 31;           // row-in-32 for MFMA operand
    const int q  = lane >> 5;           // k-half selector
    const int sw = (rl >> 1) & 3;
    const int c0 = ((0 + 2 * 0 + q) ^ sw) * 16;   // ks=0 chunk byte offset
    const int c1 = ((2 + q) ^ sw) * 16;           // ks=1 chunk byte offset

    // prologue: stage tile 0 into buffer 0
#pragma unroll
    for (int c = 0; c < 4; ++c) {
        gload_lds16(gA + (size_t)(c * 64) * IN_F, lA + c * 4096);
        gload_lds16(gB + (size_t)(c * 64) * IN_F, lB + c * 4096);
    }

    int buf = 0;
    for (int k0 = 0; k0 < IN_F; k0 += 64) {
        const int kn = k0 + 64;
        if (kn < IN_F) {
            signed char* nA = lA + (buf ^ 1) * 16384;
            signed char* nB = lB + (buf ^ 1) * 16384;
#pragma unroll
            for (int c = 0; c < 4; ++c) {
                gload_lds16(gA + (size_t)(c * 64) * IN_F + kn, nA + c * 4096);
                gload_lds16(gB + (size_t)(c * 64) * IN_F + kn, nB + c * 4096);
            }
            asm volatile("s_waitcnt vmcnt(8) lgkmcnt(0)" ::: "memory");
        } else {
            asm volatile("s_waitcnt vmcnt(0) lgkmcnt(0)" ::: "memory");
        }
        asm volatile("s_barrier" ::: "memory");   // tile-k loads visible to all

        const signed char* pA = As + buf * 16384 + (wm + rl) * 64;
        const signed char* pB = Bs + buf * 16384 + (wn + rl) * 64;
#pragma unroll
        for (int ks = 0; ks < 2; ++ks) {
            const int cb = ks ? c1 : c0;
            v4i a[4], b[4];
#pragma unroll
            for (int i = 0; i < 4; ++i)
                a[i] = *(const v4i*)(pA + i * 32 * 64 + cb);
#pragma unroll
            for (int j = 0; j < 4; ++j)
                b[j] = *(const v4i*)(pB + j * 32 * 64 + cb);
#pragma unroll
            for (int i = 0; i < 4; ++i)
#pragma unroll
                for (int j = 0; j < 4; ++j)
                    acc[i][j] = __builtin_amdgcn_mfma_i32_32x32x32_i8(a[i], b[j], acc[i][j], 0, 0, 0);
        }

        asm volatile("s_waitcnt lgkmcnt(0)" ::: "memory");  // own reads landed
        asm volatile("s_barrier" ::: "memory");             // safe to overwrite next buf
        buf ^= 1;
    }

    // epilogue: C/D layout col=lane&31, row=(reg&3)+8*(reg>>2)+4*(lane>>5)
    const float rws = 1.0f / wscale[0];
    const int colBase = n0 + wn + rl;
#pragma unroll
    for (int i = 0; i < 4; ++i) {
#pragma unroll
        for (int reg = 0; reg < 16; ++reg) {
            const int row = m0 + wm + i * 32 + (reg & 3) + 8 * (reg >> 2) + 4 * q;
            const float rs = recip_s[row] * rws;
#pragma unroll
            for (int j = 0; j < 4; ++j) {
                const int col = colBase + j * 32;
                out[(size_t)row * OUT_F + col] = (float)acc[i][j][reg] * rs + bias[col];
            }
        }
    }
}

extern "C" void kernel_launch(void* const* d_in, const int* in_sizes, int n_in,
                              void* d_out, int out_size, void* d_ws, size_t ws_size,
                              hipStream_t stream) {
    const float* x      = (const float*)d_in[0];
    const int*   w      = (const int*)d_in[1];
    const float* wscale = (const float*)d_in[2];
    const float* bias   = (const float*)d_in[3];
    float* out = (float*)d_out;

    signed char* xq = (signed char*)d_ws;                          // 32 MB
    signed char* w8 = xq + (size_t)TOKENS * IN_F;                  // 64 MB
    float* recip_s  = (float*)(w8 + (size_t)OUT_F * IN_F);         // 16 KB

    quant_kernel<<<TOKENS, 256, 0, stream>>>(x, xq, recip_s);
    pack_w<<<(int)(((size_t)OUT_F * IN_F) / 4 / 256), 256, 0, stream>>>(w, (unsigned int*)w8);
    dim3 grid(OUT_F / 256, TOKENS / 256);
    gemm_kernel<<<grid, 256, 0, stream>>>(xq, w8, recip_s, wscale, bias, out);
}

// Round 6
// 845.687 us; speedup vs baseline: 1.0743x; 1.0743x over previous
//
#include <hip/hip_runtime.h>

#define TOKENS 4096
#define IN_F   8192
#define OUT_F  8192

typedef int v4i  __attribute__((ext_vector_type(4)));
typedef int v16i __attribute__((ext_vector_type(16)));

__device__ __forceinline__ void gload_lds16(const void* g, void* l) {
    __builtin_amdgcn_global_load_lds(
        (const __attribute__((address_space(1))) void*)g,
        (__attribute__((address_space(3))) void*)l, 16, 0, 0);
}

// ---------------- Kernel 1: per-row absmax + int8 quantize ----------------
__global__ __launch_bounds__(256) void quant_kernel(const float* __restrict__ x,
                                                    signed char* __restrict__ xq,
                                                    float* __restrict__ recip_s) {
    const int row = blockIdx.x;
    const int t   = threadIdx.x;
    const float4* xr = (const float4*)(x + (size_t)row * IN_F);
    float4 v[8];
    float m = 0.f;
#pragma unroll
    for (int i = 0; i < 8; ++i) {
        v[i] = xr[t + 256 * i];
        m = fmaxf(m, fmaxf(fmaxf(fabsf(v[i].x), fabsf(v[i].y)),
                           fmaxf(fabsf(v[i].z), fabsf(v[i].w))));
    }
#pragma unroll
    for (int off = 32; off > 0; off >>= 1)
        m = fmaxf(m, __shfl_xor(m, off));
    __shared__ float wmax[4];
    if ((t & 63) == 0) wmax[t >> 6] = m;
    __syncthreads();
    m = fmaxf(fmaxf(wmax[0], wmax[1]), fmaxf(wmax[2], wmax[3]));
    m = fmaxf(m, 1e-5f);
    const float s = 127.0f / m;          // matches ref: s = 127/clip(max,1e-5)
    if (t == 0) recip_s[row] = m / 127.0f;
    unsigned int* out = (unsigned int*)(xq + (size_t)row * IN_F);
#pragma unroll
    for (int i = 0; i < 8; ++i) {
        int a = (int)fminf(fmaxf(rintf(v[i].x * s), -128.f), 127.f);
        int b = (int)fminf(fmaxf(rintf(v[i].y * s), -128.f), 127.f);
        int c = (int)fminf(fmaxf(rintf(v[i].z * s), -128.f), 127.f);
        int d = (int)fminf(fmaxf(rintf(v[i].w * s), -128.f), 127.f);
        out[t + 256 * i] = (a & 255) | ((b & 255) << 8) | ((c & 255) << 16) | ((d & 255) << 24);
    }
}

// ---------------- Kernel 2: weight int32 {0,1} -> int8 ----------------
__global__ __launch_bounds__(256) void pack_w(const int* __restrict__ w,
                                              unsigned int* __restrict__ w8) {
    const size_t idx = (size_t)blockIdx.x * 256 + threadIdx.x;
    int4 a = ((const int4*)w)[idx];
    w8[idx] = (a.x & 255) | ((a.y & 255) << 8) | ((a.z & 255) << 16) | ((a.w & 255) << 24);
}

// ---------------- Kernel 3: i8 GEMM, 128x256 block, 64x128/wave -----------
// mfma_i32_32x32x32_i8, 2x4 tiles/wave, BK=64 (2 k-steps of 32).
// FRAGMENT-LINEAR LDS: each MFMA fragment is a contiguous 1KB block; every
// ds_read is (uniform base + lane*16) -> structurally conflict-free.
//   A buffer (8KB/tile):  block(wmHalf,i,ks) at ((wmHalf*2+i)*2+ks)*1024
//   B buffer (16KB/tile): block(wnHalf,j,ks) at ((wnHalf*4+j)*2+ks)*1024
// Staging thread t (call c) sources global row = c*64 + ((t>>7)&1)*32 + (t&31),
// k-chunk = ((t>>6)&1)*32 + ((t>>5)&1)*16, writing LDS at c*4096 + t*16.
// Pipeline (1 raw barrier/iter): frags of next k-step read before MFMA of
// current; vmcnt(0) drains tile loads issued one full iteration earlier.
__global__ __launch_bounds__(256, 2) void gemm_kernel(const signed char* __restrict__ A,
                                                      const signed char* __restrict__ B,
                                                      const float* __restrict__ recip_s,
                                                      const float* __restrict__ wscale,
                                                      const float* __restrict__ bias,
                                                      float* __restrict__ out) {
    __shared__ signed char As[2 * 8192];    // 16 KB
    __shared__ signed char Bs[2 * 16384];   // 32 KB
    const int t    = threadIdx.x;
    const int wave = t >> 6;
    const int lane = t & 63;
    const int m0 = blockIdx.y * 128;
    const int n0 = blockIdx.x * 256;
    const int wmHalf = wave >> 1;           // wm = wmHalf*64
    const int wnHalf = wave & 1;            // wn = wnHalf*128

    v16i acc[2][4] = {};                    // 128 acc regs

    // staging source decomposition (fragment-linear)
    const int rowOff = ((t >> 7) & 1) * 32 + (t & 31);
    const int kOff   = ((t >> 6) & 1) * 32 + ((t >> 5) & 1) * 16;
    const signed char* gA = A + (size_t)(m0 + rowOff) * IN_F + kOff;
    const signed char* gB = B + (size_t)(n0 + rowOff) * IN_F + kOff;
    signed char* lA = As + t * 16;
    signed char* lB = Bs + t * 16;

    // fragment read bases (linear: uniform + lane*16)
    const signed char* aBase = As + wmHalf * 4096 + lane * 16;
    const signed char* bBase = Bs + wnHalf * 8192 + lane * 16;

#define STAGE(KC, BSEL) do {                                          \
        signed char* dA = lA + (BSEL) * 8192;                         \
        signed char* dB = lB + (BSEL) * 16384;                        \
        gload_lds16(gA + (size_t)(KC), dA);                           \
        gload_lds16(gA + (size_t)64 * IN_F + (KC), dA + 4096);        \
        gload_lds16(gB + (size_t)(KC), dB);                           \
        gload_lds16(gB + (size_t)64 * IN_F + (KC), dB + 4096);       \
        gload_lds16(gB + (size_t)128 * IN_F + (KC), dB + 8192);      \
        gload_lds16(gB + (size_t)192 * IN_F + (KC), dB + 12288);     \
    } while (0)

#define READ_FRAGS(AV, BV, BSEL, KS) do {                                             \
        _Pragma("unroll")                                                             \
        for (int i = 0; i < 2; ++i)                                                   \
            AV[i] = *(const v4i*)(aBase + (BSEL) * 8192 + i * 2048 + (KS) * 1024);    \
        _Pragma("unroll")                                                             \
        for (int j = 0; j < 4; ++j)                                                   \
            BV[j] = *(const v4i*)(bBase + (BSEL) * 16384 + j * 2048 + (KS) * 1024);   \
    } while (0)

#define DO_MFMA(AV, BV) do {                                                          \
        _Pragma("unroll")                                                             \
        for (int i = 0; i < 2; ++i)                                                   \
            _Pragma("unroll")                                                         \
            for (int j = 0; j < 4; ++j)                                               \
                acc[i][j] = __builtin_amdgcn_mfma_i32_32x32x32_i8(AV[i], BV[j],       \
                                                                  acc[i][j], 0, 0, 0);\
    } while (0)

    v4i a0[2], b0[4], a1[2], b1[4];

    // prologue: tile 0 -> buf 0, publish, read its ks0 frags, launch tile 1
    STAGE(0, 0);
    asm volatile("s_waitcnt vmcnt(0)" ::: "memory");
    asm volatile("s_barrier" ::: "memory");
    READ_FRAGS(a0, b0, 0, 0);
    STAGE(64, 1);

    int buf = 0;
    for (int k0 = 0; k0 < IN_F - 64; k0 += 64) {
        READ_FRAGS(a1, b1, buf, 1);                   // ks1 frags of tile k
        DO_MFMA(a0, b0);                              // ks0 compute (overlaps reads)
        asm volatile("s_waitcnt vmcnt(0) lgkmcnt(0)" ::: "memory");
        asm volatile("s_barrier" ::: "memory");       // tile k+1 published; buf free
        READ_FRAGS(a0, b0, buf ^ 1, 0);               // ks0 frags of tile k+1
        if (k0 + 128 < IN_F) STAGE(k0 + 128, buf);    // tile k+2 -> buf
        DO_MFMA(a1, b1);                              // ks1 compute (overlaps all)
        buf ^= 1;
    }
    // last tile (in buf, ks0 frags in a0/b0)
    READ_FRAGS(a1, b1, buf, 1);
    DO_MFMA(a0, b0);
    DO_MFMA(a1, b1);

    // epilogue: 32x32 C/D layout col=lane&31, row=(reg&3)+8*(reg>>2)+4*(lane>>5)
    const float rws = 1.0f / wscale[0];
    const int rl = lane & 31;
    const int q  = lane >> 5;
    const int colBase = n0 + wnHalf * 128 + rl;
#pragma unroll
    for (int i = 0; i < 2; ++i) {
#pragma unroll
        for (int reg = 0; reg < 16; ++reg) {
            const int row = m0 + wmHalf * 64 + i * 32 + (reg & 3) + 8 * (reg >> 2) + 4 * q;
            const float rs = recip_s[row] * rws;
#pragma unroll
            for (int j = 0; j < 4; ++j) {
                const int col = colBase + j * 32;
                out[(size_t)row * OUT_F + col] = (float)acc[i][j][reg] * rs + bias[col];
            }
        }
    }
#undef STAGE
#undef READ_FRAGS
#undef DO_MFMA
}

extern "C" void kernel_launch(void* const* d_in, const int* in_sizes, int n_in,
                              void* d_out, int out_size, void* d_ws, size_t ws_size,
                              hipStream_t stream) {
    const float* x      = (const float*)d_in[0];
    const int*   w      = (const int*)d_in[1];
    const float* wscale = (const float*)d_in[2];
    const float* bias   = (const float*)d_in[3];
    float* out = (float*)d_out;

    signed char* xq = (signed char*)d_ws;                          // 32 MB
    signed char* w8 = xq + (size_t)TOKENS * IN_F;                  // 64 MB
    float* recip_s  = (float*)(w8 + (size_t)OUT_F * IN_F);         // 16 KB

    quant_kernel<<<TOKENS, 256, 0, stream>>>(x, xq, recip_s);
    pack_w<<<(int)(((size_t)OUT_F * IN_F) / 4 / 256), 256, 0, stream>>>(w, (unsigned int*)w8);
    dim3 grid(OUT_F / 256, TOKENS / 128);
    gemm_kernel<<<grid, 256, 0, stream>>>(xq, w8, recip_s, wscale, bias, out);
}